// Round 3
// baseline (157.287 us; speedup 1.0000x reference)
//
#include <hip/hip_runtime.h>
#include <hip/hip_bf16.h>

// Problem constants: B=8, N=128, T=64, EMBED=64, HEADS=8, HEAD_DIM=8
// V/K/Q/Out layout: (b, n, t, c) fp32, element strides (524288, 4096, 64, 1).
// Evidence (rounds 0-2): inputs fp32, output fp32 (ref bf16-quantized for threshold only).

__global__ __launch_bounds__(512, 2)
void sattn_kernel(const float* __restrict__ V,
                  const float* __restrict__ K,
                  const float* __restrict__ Q,
                  const float* __restrict__ Wv,
                  const float* __restrict__ Wk,
                  const float* __restrict__ Wq,
                  const float* __restrict__ Wo,
                  const float* __restrict__ bo,
                  float* __restrict__ Out)
{
    // 64 KB LDS: projected K rows [0,8192), projected V rows [8192,16384)
    // row layout: [n][c] with c = h*8+e, stride 64 floats
    __shared__ float smem[16384];
    float* sK = smem;
    float* sV = smem + 8192;

    const int tid  = threadIdx.x;
    const int bt   = blockIdx.x;
    const int b    = bt >> 6;
    const int t    = bt & 63;
    const long base = (long)b * 524288 + t * 64;   // (b, n=0, t, c=0)

    // ---- Phase 1: load raw K/V (8-float head-chunks), project, store to LDS ----
    {
        int nn_[2], hh_[2];
        float rawk[2][8], rawv[2][8];
        #pragma unroll
        for (int i = 0; i < 2; ++i){
            int id8 = i*512 + tid;          // chunk index 0..1023
            int n = id8 >> 3, h = id8 & 7;
            nn_[i] = n; hh_[i] = h;
            const float* pk = K + base + n*4096 + h*8;
            const float* pv = V + base + n*4096 + h*8;
            float4 ka = *(const float4*)pk;
            float4 kb = *(const float4*)(pk+4);
            float4 va = *(const float4*)pv;
            float4 vb = *(const float4*)(pv+4);
            rawk[i][0]=ka.x; rawk[i][1]=ka.y; rawk[i][2]=ka.z; rawk[i][3]=ka.w;
            rawk[i][4]=kb.x; rawk[i][5]=kb.y; rawk[i][6]=kb.z; rawk[i][7]=kb.w;
            rawv[i][0]=va.x; rawv[i][1]=va.y; rawv[i][2]=va.z; rawv[i][3]=va.w;
            rawv[i][4]=vb.x; rawv[i][5]=vb.y; rawv[i][6]=vb.z; rawv[i][7]=vb.w;
        }
        #pragma unroll
        for (int e = 0; e < 8; ++e){
            const float4 wka = *(const float4*)(Wk + e*8);
            const float4 wkb = *(const float4*)(Wk + e*8 + 4);
            const float4 wva = *(const float4*)(Wv + e*8);
            const float4 wvb = *(const float4*)(Wv + e*8 + 4);
            #pragma unroll
            for (int i = 0; i < 2; ++i){
                float sk = rawk[i][0]*wka.x + rawk[i][1]*wka.y + rawk[i][2]*wka.z + rawk[i][3]*wka.w
                         + rawk[i][4]*wkb.x + rawk[i][5]*wkb.y + rawk[i][6]*wkb.z + rawk[i][7]*wkb.w;
                float sv = rawv[i][0]*wva.x + rawv[i][1]*wva.y + rawv[i][2]*wva.z + rawv[i][3]*wva.w
                         + rawv[i][4]*wvb.x + rawv[i][5]*wvb.y + rawv[i][6]*wvb.z + rawv[i][7]*wvb.w;
                sK[nn_[i]*64 + hh_[i]*8 + e] = sk;
                sV[nn_[i]*64 + hh_[i]*8 + e] = sv;
            }
        }
    }

    // ---- Phase 2: per-thread q projection (thread owns row n, heads 2g, 2g+1) ----
    const int n = tid >> 2;
    const int g = tid & 3;
    float qp[16];
    {
        const float* pq = Q + base + n*4096 + g*16;
        float rawq[16];
        float4 qa = *(const float4*)pq;
        float4 qb = *(const float4*)(pq+4);
        float4 qc = *(const float4*)(pq+8);
        float4 qd = *(const float4*)(pq+12);
        rawq[0]=qa.x; rawq[1]=qa.y; rawq[2]=qa.z; rawq[3]=qa.w;
        rawq[4]=qb.x; rawq[5]=qb.y; rawq[6]=qb.z; rawq[7]=qb.w;
        rawq[8]=qc.x; rawq[9]=qc.y; rawq[10]=qc.z; rawq[11]=qc.w;
        rawq[12]=qd.x; rawq[13]=qd.y; rawq[14]=qd.z; rawq[15]=qd.w;
        #pragma unroll
        for (int e = 0; e < 8; ++e){
            const float4 wa = *(const float4*)(Wq + e*8);
            const float4 wb = *(const float4*)(Wq + e*8 + 4);
            qp[e]   = rawq[0]*wa.x + rawq[1]*wa.y + rawq[2]*wa.z + rawq[3]*wa.w
                    + rawq[4]*wb.x + rawq[5]*wb.y + rawq[6]*wb.z + rawq[7]*wb.w;
            qp[8+e] = rawq[8]*wa.x + rawq[9]*wa.y + rawq[10]*wa.z + rawq[11]*wa.w
                    + rawq[12]*wb.x + rawq[13]*wb.y + rawq[14]*wb.z + rawq[15]*wb.w;
        }
    }

    __syncthreads();

    // ---- Phase 3: attention over spatial axis (softmax without max-sub:
    //      energies/8 bounded ±~3 by construction; exp2 clamped for safety) ----
    float acc[16];
    #pragma unroll
    for (int i = 0; i < 16; ++i) acc[i] = 0.f;
    float l0 = 0.f, l1 = 0.f;
    const float sc = 0.18033688011112043f;  // (1/8) * log2(e)
    const int koff = g * 16;

    #pragma unroll 4
    for (int j = 0; j < 128; ++j){
        const float* kr = sK + j*64 + koff;
        const float* vr = sV + j*64 + koff;
        float4 ka = *(const float4*)(kr);
        float4 kb = *(const float4*)(kr+4);
        float4 kc = *(const float4*)(kr+8);
        float4 kd = *(const float4*)(kr+12);
        float e0 = qp[0]*ka.x + qp[1]*ka.y + qp[2]*ka.z + qp[3]*ka.w
                 + qp[4]*kb.x + qp[5]*kb.y + qp[6]*kb.z + qp[7]*kb.w;
        float e1 = qp[8]*kc.x + qp[9]*kc.y + qp[10]*kc.z + qp[11]*kc.w
                 + qp[12]*kd.x + qp[13]*kd.y + qp[14]*kd.z + qp[15]*kd.w;
        float w0 = __builtin_amdgcn_exp2f(fminf(e0 * sc, 30.f));
        float w1 = __builtin_amdgcn_exp2f(fminf(e1 * sc, 30.f));
        l0 += w0; l1 += w1;
        float4 va = *(const float4*)(vr);
        float4 vb = *(const float4*)(vr+4);
        float4 vc = *(const float4*)(vr+8);
        float4 vd = *(const float4*)(vr+12);
        acc[0]  += w0*va.x; acc[1]  += w0*va.y; acc[2]  += w0*va.z; acc[3]  += w0*va.w;
        acc[4]  += w0*vb.x; acc[5]  += w0*vb.y; acc[6]  += w0*vb.z; acc[7]  += w0*vb.w;
        acc[8]  += w1*vc.x; acc[9]  += w1*vc.y; acc[10] += w1*vc.z; acc[11] += w1*vc.w;
        acc[12] += w1*vd.x; acc[13] += w1*vd.y; acc[14] += w1*vd.z; acc[15] += w1*vd.w;
    }

    __syncthreads();   // all reads of sK/sV complete

    // ---- Phase 4: normalize, write concat attention rows into sK region ----
    {
        float i0 = 1.0f / l0;
        float i1 = 1.0f / l1;
        float* crow = sK + n*64 + koff;
        *(float4*)(crow)    = make_float4(acc[0]*i0,  acc[1]*i0,  acc[2]*i0,  acc[3]*i0);
        *(float4*)(crow+4)  = make_float4(acc[4]*i0,  acc[5]*i0,  acc[6]*i0,  acc[7]*i0);
        *(float4*)(crow+8)  = make_float4(acc[8]*i1,  acc[9]*i1,  acc[10]*i1, acc[11]*i1);
        *(float4*)(crow+12) = make_float4(acc[12]*i1, acc[13]*i1, acc[14]*i1, acc[15]*i1);
    }

    __syncthreads();

    // ---- Phase 5: fc_out. thread owns output column o = tid&63 for 16 rows ----
    const int o  = tid & 63;
    const int wq = tid >> 6;           // wave id 0..7; rows n = r*8 + wq
    float partial[16];
    const float bov = bo[o];
    #pragma unroll
    for (int r = 0; r < 16; ++r) partial[r] = bov;

    #pragma unroll
    for (int cc = 0; cc < 4; ++cc){
        const float* wrow = Wo + o*64 + cc*16;
        float4 w0 = *(const float4*)(wrow);
        float4 w1 = *(const float4*)(wrow+4);
        float4 w2 = *(const float4*)(wrow+8);
        float4 w3 = *(const float4*)(wrow+12);
        #pragma unroll
        for (int r = 0; r < 16; ++r){
            const float* cf = sK + (r*8 + wq)*64 + cc*16;  // wave-broadcast read
            float4 c0 = *(const float4*)cf;
            float4 c1 = *(const float4*)(cf+4);
            float4 c2 = *(const float4*)(cf+8);
            float4 c3 = *(const float4*)(cf+12);
            partial[r] += c0.x*w0.x + c0.y*w0.y + c0.z*w0.z + c0.w*w0.w
                        + c1.x*w1.x + c1.y*w1.y + c1.z*w1.z + c1.w*w1.w
                        + c2.x*w2.x + c2.y*w2.y + c2.z*w2.z + c2.w*w2.w
                        + c3.x*w3.x + c3.y*w3.y + c3.z*w3.z + c3.w*w3.w;
        }
    }

    #pragma unroll
    for (int r = 0; r < 16; ++r){
        int nn = r*8 + wq;
        Out[base + nn*4096 + o] = partial[r];
    }
}

extern "C" void kernel_launch(void* const* d_in, const int* in_sizes, int n_in,
                              void* d_out, int out_size, void* d_ws, size_t ws_size,
                              hipStream_t stream)
{
    const float* V  = (const float*)d_in[0];
    const float* K  = (const float*)d_in[1];
    const float* Q  = (const float*)d_in[2];
    const float* Wv = (const float*)d_in[3];
    const float* Wk = (const float*)d_in[4];
    const float* Wq = (const float*)d_in[5];
    const float* Wo = (const float*)d_in[6];
    const float* bo = (const float*)d_in[7];

    sattn_kernel<<<dim3(512), dim3(512), 0, stream>>>(
        V, K, Q, Wv, Wk, Wq, Wo, bo, (float*)d_out);
}

// Round 4
// 147.437 us; speedup vs baseline: 1.0668x; 1.0668x over previous
//
#include <hip/hip_runtime.h>

// Problem constants: B=8, N=128, T=64, EMBED=64, HEADS=8, HEAD_DIM=8
// V/K/Q/Out layout: (b, n, t, c) fp32, element strides (524288, 4096, 64, 1).
// Round-3 evidence: LDS return-BW bound (8x b128/iter, 4.3GB j-loop traffic ~ 55us
// at 128B/cyc/CU; measured 83us). This version: f16 LDS (half bytes), v_dot2_f32_f16
// (fp32 accum), 1 head/thread, 40KB LDS -> 4 blocks/CU = 32 waves/CU.

typedef _Float16 h2 __attribute__((ext_vector_type(2)));
using uint = unsigned int;

#if __has_builtin(__builtin_amdgcn_fdot2)
__device__ __forceinline__ float dot2(h2 a, h2 b, float c){ return __builtin_amdgcn_fdot2(a, b, c, false); }
#else
__device__ __forceinline__ float dot2(h2 a, h2 b, float c){ return (float)a.x*(float)b.x + (float)a.y*(float)b.y + c; }
#endif

__device__ __forceinline__ uint packh2(float a, float b){
    union { h2 h; uint u; } cv;
    cv.h.x = (_Float16)a; cv.h.y = (_Float16)b;
    return cv.u;
}
__device__ __forceinline__ h2 ash2(uint u){
    union { uint u; h2 h; } cv; cv.u = u; return cv.h;
}

__global__ __launch_bounds__(512, 8)
void sattn_kernel(const float* __restrict__ V,
                  const float* __restrict__ K,
                  const float* __restrict__ Q,
                  const float* __restrict__ Wv,
                  const float* __restrict__ Wk,
                  const float* __restrict__ Wq,
                  const float* __restrict__ Wo,
                  const float* __restrict__ bo,
                  float* __restrict__ Out)
{
    // LDS (dwords): [0,4096) K' f16 128x64 | [4096,8192) V' f16 | [8192,10240) Wo f16
    // C' (64x64 f16) overlays [0,2048) after the j-loop. Total 40 KB -> 4 blocks/CU.
    __shared__ uint smem[10240];

    const int tid  = threadIdx.x;
    const int bid  = blockIdx.x;
    const int half = bid & 1;            // which 64-query half this block owns
    const int bt   = bid >> 1;
    const int b    = bt >> 6;
    const int t    = bt & 63;
    const long base = (long)b * 524288 + t * 64;

    // ---- stage Wo as packed f16 (coalesced read, conflict-free b128 write) ----
    {
        const float* wsrc = Wo + tid*8;
        float4 a = *(const float4*)wsrc;
        float4 c = *(const float4*)(wsrc + 4);
        uint4 p = make_uint4(packh2(a.x,a.y), packh2(a.z,a.w),
                             packh2(c.x,c.y), packh2(c.z,c.w));
        *(uint4*)&smem[8192 + tid*4] = p;
    }

    // ---- stage projected K', V' as f16 (full 128 keys, all 8 heads) ----
    #pragma unroll
    for (int i = 0; i < 2; ++i){
        int id = i*512 + tid;            // chunk 0..1023 = (n, h)
        int cn = id >> 3, ch = id & 7;
        const float* pk = K + base + cn*4096 + ch*8;
        const float* pv = V + base + cn*4096 + ch*8;
        float4 ka = *(const float4*)pk, kb = *(const float4*)(pk+4);
        float4 va = *(const float4*)pv, vb = *(const float4*)(pv+4);
        float ok[8], ov[8];
        #pragma unroll
        for (int e = 0; e < 8; ++e){
            float4 wk0 = *(const float4*)(Wk + e*8), wk1 = *(const float4*)(Wk + e*8 + 4);
            float4 wv0 = *(const float4*)(Wv + e*8), wv1 = *(const float4*)(Wv + e*8 + 4);
            ok[e] = ka.x*wk0.x + ka.y*wk0.y + ka.z*wk0.z + ka.w*wk0.w
                  + kb.x*wk1.x + kb.y*wk1.y + kb.z*wk1.z + kb.w*wk1.w;
            ov[e] = va.x*wv0.x + va.y*wv0.y + va.z*wv0.z + va.w*wv0.w
                  + vb.x*wv1.x + vb.y*wv1.y + vb.z*wv1.z + vb.w*wv1.w;
        }
        uint4 pkk = make_uint4(packh2(ok[0],ok[1]), packh2(ok[2],ok[3]),
                               packh2(ok[4],ok[5]), packh2(ok[6],ok[7]));
        uint4 pvv = make_uint4(packh2(ov[0],ov[1]), packh2(ov[2],ov[3]),
                               packh2(ov[4],ov[5]), packh2(ov[6],ov[7]));
        *(uint4*)&smem[cn*32 + ch*4]        = pkk;   // lanes cover distinct bank quads
        *(uint4*)&smem[4096 + cn*32 + ch*4] = pvv;
    }

    // ---- q projection (global loads only; before the barrier) ----
    const int nl = tid >> 3;             // local query row 0..63
    const int h  = tid & 7;             // head 0..7
    const int nq = half*64 + nl;
    h2 qh[4];
    {
        const float* pq = Q + base + nq*4096 + h*8;
        float4 qa = *(const float4*)pq, qb = *(const float4*)(pq+4);
        float qf[8];
        #pragma unroll
        for (int e = 0; e < 8; ++e){
            float4 w0 = *(const float4*)(Wq + e*8), w1 = *(const float4*)(Wq + e*8 + 4);
            qf[e] = qa.x*w0.x + qa.y*w0.y + qa.z*w0.z + qa.w*w0.w
                  + qb.x*w1.x + qb.y*w1.y + qb.z*w1.z + qb.w*w1.w;
        }
        qh[0] = ash2(packh2(qf[0],qf[1]));
        qh[1] = ash2(packh2(qf[2],qf[3]));
        qh[2] = ash2(packh2(qf[4],qf[5]));
        qh[3] = ash2(packh2(qf[6],qf[7]));
    }

    __syncthreads();

    // ---- attention j-loop: 2 ds_read_b128 per iter (was 8) ----
    float acc[8];
    #pragma unroll
    for (int i = 0; i < 8; ++i) acc[i] = 0.f;
    float l = 0.f;
    const float sc = 0.18033688011112043f;   // (1/8) * log2(e)
    const int ko = h*4;

    #pragma unroll 2
    for (int j = 0; j < 128; ++j){
        uint4 kk = *(const uint4*)&smem[j*32 + ko];
        uint4 vv = *(const uint4*)&smem[4096 + j*32 + ko];
        float e = dot2(ash2(kk.x), qh[0],
                  dot2(ash2(kk.y), qh[1],
                  dot2(ash2(kk.z), qh[2],
                  dot2(ash2(kk.w), qh[3], 0.f))));
        float w = __builtin_amdgcn_exp2f(fminf(e * sc, 30.f));
        l += w;
        h2 v0 = ash2(vv.x), v1 = ash2(vv.y), v2 = ash2(vv.z), v3 = ash2(vv.w);
        acc[0] += w*(float)v0.x; acc[1] += w*(float)v0.y;
        acc[2] += w*(float)v1.x; acc[3] += w*(float)v1.y;
        acc[4] += w*(float)v2.x; acc[5] += w*(float)v2.y;
        acc[6] += w*(float)v3.x; acc[7] += w*(float)v3.y;
    }

    __syncthreads();   // all reads of sK/sV done before C' overlays sK

    // ---- write normalized C' (f16) ----
    {
        float inv = 1.0f / l;
        uint4 p = make_uint4(packh2(acc[0]*inv, acc[1]*inv), packh2(acc[2]*inv, acc[3]*inv),
                             packh2(acc[4]*inv, acc[5]*inv), packh2(acc[6]*inv, acc[7]*inv));
        *(uint4*)&smem[nl*32 + h*4] = p;
    }

    __syncthreads();

    // ---- fc: thread owns output column o for 8 rows ----
    const int o  = tid & 63;
    const int wq = tid >> 6;            // wave id 0..7
    h2 wo[32];
    #pragma unroll
    for (int i = 0; i < 8; ++i){
        uint4 u = *(const uint4*)&smem[8192 + o*32 + i*4];
        wo[i*4+0] = ash2(u.x); wo[i*4+1] = ash2(u.y);
        wo[i*4+2] = ash2(u.z); wo[i*4+3] = ash2(u.w);
    }
    const float bov = bo[o];

    #pragma unroll
    for (int r = 0; r < 8; ++r){
        int row = r*8 + wq;
        float p = bov;
        #pragma unroll
        for (int i = 0; i < 8; ++i){
            uint4 u = *(const uint4*)&smem[row*32 + i*4];   // wave-uniform broadcast
            p = dot2(ash2(u.x), wo[i*4+0], p);
            p = dot2(ash2(u.y), wo[i*4+1], p);
            p = dot2(ash2(u.z), wo[i*4+2], p);
            p = dot2(ash2(u.w), wo[i*4+3], p);
        }
        Out[base + (long)(half*64 + row)*4096 + o] = p;
    }
}

extern "C" void kernel_launch(void* const* d_in, const int* in_sizes, int n_in,
                              void* d_out, int out_size, void* d_ws, size_t ws_size,
                              hipStream_t stream)
{
    const float* V  = (const float*)d_in[0];
    const float* K  = (const float*)d_in[1];
    const float* Q  = (const float*)d_in[2];
    const float* Wv = (const float*)d_in[3];
    const float* Wk = (const float*)d_in[4];
    const float* Wq = (const float*)d_in[5];
    const float* Wo = (const float*)d_in[6];
    const float* bo = (const float*)d_in[7];

    sattn_kernel<<<dim3(1024), dim3(512), 0, stream>>>(
        V, K, Q, Wv, Wk, Wq, Wo, bo, (float*)d_out);
}

// Round 5
// 141.160 us; speedup vs baseline: 1.1142x; 1.0445x over previous
//
#include <hip/hip_runtime.h>

// Problem constants: B=8, N=128, T=64, EMBED=64, HEADS=8, HEAD_DIM=8
// V/K/Q/Out layout: (b, n, t, c) fp32, element strides (524288, 4096, 64, 1).
// Round-4 evidence: VALU-issue bound (44us busy) + LDS b128 return BW (~40us),
// conflicts from Wo o*32-stride prefetch. This version: wave=head, 2 queries/lane,
// wave-uniform broadcast K/V reads (amortized over 2 queries), padded LDS strides
// (36 dwords) for conflict-free strided access, dot2 energies, f16 LDS everywhere.

typedef _Float16 h2 __attribute__((ext_vector_type(2)));
using uint = unsigned int;

#if __has_builtin(__builtin_amdgcn_fdot2)
__device__ __forceinline__ float dot2(h2 a, h2 b, float c){ return __builtin_amdgcn_fdot2(a, b, c, false); }
#else
__device__ __forceinline__ float dot2(h2 a, h2 b, float c){ return (float)a.x*(float)b.x + (float)a.y*(float)b.y + c; }
#endif

__device__ __forceinline__ uint packh2(float a, float b){
    union { h2 h; uint u; } cv;
    cv.h.x = (_Float16)a; cv.h.y = (_Float16)b;
    return cv.u;
}
__device__ __forceinline__ h2 ash2(uint u){
    union { uint u; h2 h; } cv; cv.u = u; return cv.h;
}

// LDS dword-offset map (total 15616 dwords = 62.5 KB -> 2 blocks/CU):
//   K'  f16 128 rows x 32 dwords  @ [0, 4096)
//   V'  f16 128 rows x 36 dwords  @ [4096, 8704)   (pad: read/write quad = (row+h)&7)
//   Q'  f16 128 rows x 36 dwords  @ [8704, 13312)
//   Wo  f16  64 rows x 36 dwords  @ [13312, 15616)
//   C'  f16 128 rows x 36 dwords  @ [0, 4608)      (overlays K'/V' after j-loop)
#define KO 0
#define VO 4096
#define QO 8704
#define WOO 13312
#define CO 0

__global__ __launch_bounds__(512, 4)
void sattn_kernel(const float* __restrict__ V,
                  const float* __restrict__ K,
                  const float* __restrict__ Q,
                  const float* __restrict__ Wv,
                  const float* __restrict__ Wk,
                  const float* __restrict__ Wq,
                  const float* __restrict__ Wo,
                  const float* __restrict__ bo,
                  float* __restrict__ Out)
{
    __shared__ uint smem[15616];

    const int tid  = threadIdx.x;
    const int bid  = blockIdx.x;
    const int b    = bid >> 6;
    const int t    = bid & 63;
    const long base = (long)b * 524288 + t * 64;

    // ---- stage Wo (f16, stride 36: write quad = (o+c)&7, balanced) ----
    {
        int o = tid >> 3, c = tid & 7;
        const float* ws = Wo + o*64 + c*8;
        float4 a = *(const float4*)ws;
        float4 d = *(const float4*)(ws + 4);
        *(uint4*)&smem[WOO + o*36 + c*4] =
            make_uint4(packh2(a.x,a.y), packh2(a.z,a.w), packh2(d.x,d.y), packh2(d.z,d.w));
    }

    // ---- stage projected K', V', Q' (2 (row,head) cells per thread) ----
    #pragma unroll
    for (int i = 0; i < 2; ++i){
        int id = i*512 + tid;
        int cn = id >> 3, ch = id & 7;
        const float* pk = K + base + cn*4096 + ch*8;
        const float* pv = V + base + cn*4096 + ch*8;
        const float* pq = Q + base + cn*4096 + ch*8;
        float4 ka = *(const float4*)pk, kb = *(const float4*)(pk+4);
        float4 va = *(const float4*)pv, vb = *(const float4*)(pv+4);
        float4 qa = *(const float4*)pq, qb = *(const float4*)(pq+4);
        float ok[8], ov[8], oq[8];
        #pragma unroll
        for (int e = 0; e < 8; ++e){
            float4 wk0 = *(const float4*)(Wk + e*8), wk1 = *(const float4*)(Wk + e*8 + 4);
            float4 wv0 = *(const float4*)(Wv + e*8), wv1 = *(const float4*)(Wv + e*8 + 4);
            float4 wq0 = *(const float4*)(Wq + e*8), wq1 = *(const float4*)(Wq + e*8 + 4);
            ok[e] = ka.x*wk0.x + ka.y*wk0.y + ka.z*wk0.z + ka.w*wk0.w
                  + kb.x*wk1.x + kb.y*wk1.y + kb.z*wk1.z + kb.w*wk1.w;
            ov[e] = va.x*wv0.x + va.y*wv0.y + va.z*wv0.z + va.w*wv0.w
                  + vb.x*wv1.x + vb.y*wv1.y + vb.z*wv1.z + vb.w*wv1.w;
            oq[e] = qa.x*wq0.x + qa.y*wq0.y + qa.z*wq0.z + qa.w*wq0.w
                  + qb.x*wq1.x + qb.y*wq1.y + qb.z*wq1.z + qb.w*wq1.w;
        }
        *(uint4*)&smem[KO + cn*32 + ch*4] =
            make_uint4(packh2(ok[0],ok[1]), packh2(ok[2],ok[3]), packh2(ok[4],ok[5]), packh2(ok[6],ok[7]));
        *(uint4*)&smem[VO + cn*36 + ch*4] =
            make_uint4(packh2(ov[0],ov[1]), packh2(ov[2],ov[3]), packh2(ov[4],ov[5]), packh2(ov[6],ov[7]));
        *(uint4*)&smem[QO + cn*36 + ch*4] =
            make_uint4(packh2(oq[0],oq[1]), packh2(oq[2],oq[3]), packh2(oq[4],oq[5]), packh2(oq[6],oq[7]));
    }

    __syncthreads();

    // ---- attention: wave w = head, lane l owns queries l and 64+l ----
    const int w = tid >> 6;
    const int l = tid & 63;
    h2 q0[4], q1[4];
    {
        uint4 ua = *(const uint4*)&smem[QO + l*36 + w*4];        // quad (l+w)&7: balanced
        uint4 ub = *(const uint4*)&smem[QO + (64+l)*36 + w*4];
        q0[0]=ash2(ua.x); q0[1]=ash2(ua.y); q0[2]=ash2(ua.z); q0[3]=ash2(ua.w);
        q1[0]=ash2(ub.x); q1[1]=ash2(ub.y); q1[2]=ash2(ub.z); q1[3]=ash2(ub.w);
    }

    float acc0[8], acc1[8];
    #pragma unroll
    for (int i = 0; i < 8; ++i){ acc0[i] = 0.f; acc1[i] = 0.f; }
    float l0 = 0.f, l1 = 0.f;
    const float sc = 0.18033688011112043f;   // (1/8) * log2(e)

    #pragma unroll 2
    for (int j = 0; j < 128; ++j){
        // wave-uniform addresses -> LDS broadcast reads
        uint4 kk = *(const uint4*)&smem[KO + j*32 + w*4];
        uint4 vv = *(const uint4*)&smem[VO + j*36 + w*4];
        float e0 = dot2(ash2(kk.x), q0[0],
                   dot2(ash2(kk.y), q0[1],
                   dot2(ash2(kk.z), q0[2],
                   dot2(ash2(kk.w), q0[3], 0.f))));
        float e1 = dot2(ash2(kk.x), q1[0],
                   dot2(ash2(kk.y), q1[1],
                   dot2(ash2(kk.z), q1[2],
                   dot2(ash2(kk.w), q1[3], 0.f))));
        float w0 = __builtin_amdgcn_exp2f(fminf(e0 * sc, 30.f));
        float w1 = __builtin_amdgcn_exp2f(fminf(e1 * sc, 30.f));
        l0 += w0; l1 += w1;
        h2 v0 = ash2(vv.x), v1 = ash2(vv.y), v2 = ash2(vv.z), v3 = ash2(vv.w);
        // mixed-precision FMAs (v_fma_mix candidates)
        acc0[0] += w0*(float)v0.x; acc0[1] += w0*(float)v0.y;
        acc0[2] += w0*(float)v1.x; acc0[3] += w0*(float)v1.y;
        acc0[4] += w0*(float)v2.x; acc0[5] += w0*(float)v2.y;
        acc0[6] += w0*(float)v3.x; acc0[7] += w0*(float)v3.y;
        acc1[0] += w1*(float)v0.x; acc1[1] += w1*(float)v0.y;
        acc1[2] += w1*(float)v1.x; acc1[3] += w1*(float)v1.y;
        acc1[4] += w1*(float)v2.x; acc1[5] += w1*(float)v2.y;
        acc1[6] += w1*(float)v3.x; acc1[7] += w1*(float)v3.y;
    }

    __syncthreads();   // all reads of K'/V'/Q' complete before C' overlays

    // ---- write normalized C' (f16, stride 36: quad (row+w)&7 balanced) ----
    {
        float i0 = 1.0f / l0;
        float i1 = 1.0f / l1;
        *(uint4*)&smem[CO + l*36 + w*4] =
            make_uint4(packh2(acc0[0]*i0, acc0[1]*i0), packh2(acc0[2]*i0, acc0[3]*i0),
                       packh2(acc0[4]*i0, acc0[5]*i0), packh2(acc0[6]*i0, acc0[7]*i0));
        *(uint4*)&smem[CO + (64+l)*36 + w*4] =
            make_uint4(packh2(acc1[0]*i1, acc1[1]*i1), packh2(acc1[2]*i1, acc1[3]*i1),
                       packh2(acc1[4]*i1, acc1[5]*i1), packh2(acc1[6]*i1, acc1[7]*i1));
    }

    __syncthreads();

    // ---- fc: thread owns output column o for 16 rows ----
    const int o  = tid & 63;
    const int wq = tid >> 6;
    h2 wo[32];
    #pragma unroll
    for (int i = 0; i < 8; ++i){
        uint4 u = *(const uint4*)&smem[WOO + o*36 + i*4];   // quad (o+i)&7: balanced
        wo[i*4+0] = ash2(u.x); wo[i*4+1] = ash2(u.y);
        wo[i*4+2] = ash2(u.z); wo[i*4+3] = ash2(u.w);
    }
    const float bov = bo[o];

    #pragma unroll
    for (int r = 0; r < 16; ++r){
        int row = r*8 + wq;
        float p = bov;
        #pragma unroll
        for (int i = 0; i < 8; ++i){
            uint4 u = *(const uint4*)&smem[CO + row*36 + i*4];   // wave-uniform broadcast
            p = dot2(ash2(u.x), wo[i*4+0], p);
            p = dot2(ash2(u.y), wo[i*4+1], p);
            p = dot2(ash2(u.z), wo[i*4+2], p);
            p = dot2(ash2(u.w), wo[i*4+3], p);
        }
        Out[base + (long)row*4096 + o] = p;
    }
}

extern "C" void kernel_launch(void* const* d_in, const int* in_sizes, int n_in,
                              void* d_out, int out_size, void* d_ws, size_t ws_size,
                              hipStream_t stream)
{
    const float* V  = (const float*)d_in[0];
    const float* K  = (const float*)d_in[1];
    const float* Q  = (const float*)d_in[2];
    const float* Wv = (const float*)d_in[3];
    const float* Wk = (const float*)d_in[4];
    const float* Wq = (const float*)d_in[5];
    const float* Wo = (const float*)d_in[6];
    const float* bo = (const float*)d_in[7];

    sattn_kernel<<<dim3(512), dim3(512), 0, stream>>>(
        V, K, Q, Wv, Wk, Wq, Wo, bo, (float*)d_out);
}

// Round 7
// 114.820 us; speedup vs baseline: 1.3699x; 1.2294x over previous
//
#include <hip/hip_runtime.h>

// Problem constants: B=8, N=128, T=64, EMBED=64, HEADS=8, HEAD_DIM=8
// V/K/Q/Out layout: (b, n, t, c) fp32, element strides (524288, 4096, 64, 1).
// Round-5 evidence: MfmaUtil=0 with VALU(35us)+LDS(30us) co-bound on matmul work.
// This version: MFMA everywhere. E^T = K'Q'^T trick keeps P in A-layout for PV
// (no LDS transpose). wave = head; fc via 16 MFMAs/wave. f16 LDS, f32 accum.
// Round-6 fix: gfx950 builtin spelling is ...16x16x16f16 (no underscore).

typedef _Float16 half4 __attribute__((ext_vector_type(4)));
typedef float    f32x4 __attribute__((ext_vector_type(4)));

#define MFMA16(a,b,c) __builtin_amdgcn_mfma_f32_16x16x16f16((a),(b),(c),0,0,0)

__device__ __forceinline__ unsigned short f2h(float f){
    union { _Float16 h; unsigned short u; } c; c.h = (_Float16)f; return c.u;
}

// LDS offsets in halves (ushort units). Total 37640 halves = 75280 B -> 2 blocks/CU.
#define ZS 0          //    8 halves zero scratch (b64-read target for padded lanes)
#define KB 8          // K' per head: [128 k][8 d]            8*1024
#define QB 8200       // Q' per head: [128 q][8 d] (pre-scaled by sc)
#define VB 16392      // V'^T per head: [8 e][128 k]
#define CB 24584      // C': [128 n][68]  (stride 68 -> conflict-free fc reads)
#define WB 33288      // Wo: [64 o][68]
#define LDS_TOTAL 37640

__global__ __launch_bounds__(512, 4)
void sattn_kernel(const float* __restrict__ V,
                  const float* __restrict__ K,
                  const float* __restrict__ Q,
                  const float* __restrict__ Wv,
                  const float* __restrict__ Wk,
                  const float* __restrict__ Wq,
                  const float* __restrict__ Wo,
                  const float* __restrict__ bo,
                  float* __restrict__ Out)
{
    __shared__ __align__(16) unsigned short smem[LDS_TOTAL];

    const int tid  = threadIdx.x;
    const int bid  = blockIdx.x;
    const int b    = bid >> 6;
    const int t    = bid & 63;
    const long base = (long)b * 524288 + t * 64;
    const float SC = 0.18033688011112043f;   // (1/8) * log2(e), folded into Q'

    // ---- zero scratch ----
    if (tid < 4) *(unsigned int*)(smem + tid*2) = 0u;

    // ---- stage Wo f16 [64 o][68] ----
    {
        int o = tid >> 3, c8 = tid & 7;
        const float* ws = Wo + o*64 + c8*8;
        float4 a = *(const float4*)ws;
        float4 d = *(const float4*)(ws + 4);
        half4 h0; h0.x=(_Float16)a.x; h0.y=(_Float16)a.y; h0.z=(_Float16)a.z; h0.w=(_Float16)a.w;
        half4 h1; h1.x=(_Float16)d.x; h1.y=(_Float16)d.y; h1.z=(_Float16)d.z; h1.w=(_Float16)d.w;
        *(half4*)(smem + WB + o*68 + c8*8)     = h0;   // 8-B aligned
        *(half4*)(smem + WB + o*68 + c8*8 + 4) = h1;
    }

    // ---- stage projected K', Q' (x sc), V'^T as f16 (2 cells/thread, sequential) ----
    for (int i = 0; i < 2; ++i){
        int id = i*512 + tid;
        int cn = id >> 3, ch = id & 7;          // key/query row, head
        const float* pk = K + base + cn*4096 + ch*8;
        const float* pv = V + base + cn*4096 + ch*8;
        const float* pq = Q + base + cn*4096 + ch*8;
        float4 ka = *(const float4*)pk, kb = *(const float4*)(pk+4);
        float4 va = *(const float4*)pv, vb = *(const float4*)(pv+4);
        float4 qa = *(const float4*)pq, qb = *(const float4*)(pq+4);
        float ok[8], ov[8], oq[8];
        #pragma unroll
        for (int e = 0; e < 8; ++e){
            float4 wk0 = *(const float4*)(Wk + e*8), wk1 = *(const float4*)(Wk + e*8 + 4);
            float4 wv0 = *(const float4*)(Wv + e*8), wv1 = *(const float4*)(Wv + e*8 + 4);
            float4 wq0 = *(const float4*)(Wq + e*8), wq1 = *(const float4*)(Wq + e*8 + 4);
            ok[e] = ka.x*wk0.x + ka.y*wk0.y + ka.z*wk0.z + ka.w*wk0.w
                  + kb.x*wk1.x + kb.y*wk1.y + kb.z*wk1.z + kb.w*wk1.w;
            ov[e] = va.x*wv0.x + va.y*wv0.y + va.z*wv0.z + va.w*wv0.w
                  + vb.x*wv1.x + vb.y*wv1.y + vb.z*wv1.z + vb.w*wv1.w;
            oq[e] = (qa.x*wq0.x + qa.y*wq0.y + qa.z*wq0.z + qa.w*wq0.w
                  +  qb.x*wq1.x + qb.y*wq1.y + qb.z*wq1.z + qb.w*wq1.w) * SC;
        }
        half4 k0; k0.x=(_Float16)ok[0]; k0.y=(_Float16)ok[1]; k0.z=(_Float16)ok[2]; k0.w=(_Float16)ok[3];
        half4 k1; k1.x=(_Float16)ok[4]; k1.y=(_Float16)ok[5]; k1.z=(_Float16)ok[6]; k1.w=(_Float16)ok[7];
        half4 q0; q0.x=(_Float16)oq[0]; q0.y=(_Float16)oq[1]; q0.z=(_Float16)oq[2]; q0.w=(_Float16)oq[3];
        half4 q1; q1.x=(_Float16)oq[4]; q1.y=(_Float16)oq[5]; q1.z=(_Float16)oq[6]; q1.w=(_Float16)oq[7];
        *(half4*)(smem + KB + ch*1024 + cn*8)     = k0;
        *(half4*)(smem + KB + ch*1024 + cn*8 + 4) = k1;
        *(half4*)(smem + QB + ch*1024 + cn*8)     = q0;
        *(half4*)(smem + QB + ch*1024 + cn*8 + 4) = q1;
        #pragma unroll
        for (int e = 0; e < 8; ++e)
            smem[VB + ch*1024 + e*128 + cn] = f2h(ov[e]);
    }

    __syncthreads();

    // ---- attention: wave = head h ----
    const int h    = tid >> 6;
    const int q16  = tid & 15;          // lane & 15
    const int quad = (tid & 63) >> 4;   // lane >> 4
    const f32x4 zz = {0.f, 0.f, 0.f, 0.f};

    // K' A-fragments (8 k-tiles, held): A[m=l&15][k=quad*4+i], quads 2,3 -> zero
    half4 kf[8];
    #pragma unroll
    for (int mt = 0; mt < 8; ++mt){
        int a = KB + h*1024 + (mt*16 + q16)*8 + quad*4;
        if (quad >= 2) a = ZS;
        kf[mt] = *(const half4*)(smem + a);
    }
    // V'^T B-fragments (8 k-steps, held): B[k=quad*4+i][n=e=l&15], e>=8 -> zero
    half4 vf[8];
    #pragma unroll
    for (int s = 0; s < 8; ++s){
        int a = VB + h*1024 + q16*128 + s*16 + quad*4;
        if (q16 >= 8) a = ZS;
        vf[s] = *(const half4*)(smem + a);
    }

    #pragma unroll 1
    for (int qs = 0; qs < 8; ++qs){
        // Q' B-fragment for this strip: B[k=d][n=q], quads 2,3 -> zero
        int qa = QB + h*1024 + (qs*16 + q16)*8 + quad*4;
        if (quad >= 2) qa = ZS;
        half4 qf = *(const half4*)(smem + qa);

        // E^T strip: 8 independent MFMAs (m-tile = key tile)
        f32x4 acc[8];
        #pragma unroll
        for (int mt = 0; mt < 8; ++mt)
            acc[mt] = MFMA16(kf[mt], qf, zz);

        // softmax (no max-sub: |E*sc| <~ 3 by construction): exp2, sum, normalize
        float s = 0.f;
        #pragma unroll
        for (int mt = 0; mt < 8; ++mt){
            #pragma unroll
            for (int r = 0; r < 4; ++r){
                float p = __builtin_amdgcn_exp2f(acc[mt][r]);
                acc[mt][r] = p;
                s += p;
            }
        }
        s += __shfl_xor(s, 16, 64);
        s += __shfl_xor(s, 32, 64);
        float inv = 1.0f / s;

        // pack normalized P into A-fragments (exact layout match for PV)
        half4 pf[8];
        #pragma unroll
        for (int mt = 0; mt < 8; ++mt){
            pf[mt].x = (_Float16)(acc[mt][0]*inv);
            pf[mt].y = (_Float16)(acc[mt][1]*inv);
            pf[mt].z = (_Float16)(acc[mt][2]*inv);
            pf[mt].w = (_Float16)(acc[mt][3]*inv);
        }

        // PV: chained accumulation over 8 k-steps
        f32x4 o = zz;
        #pragma unroll
        for (int s8 = 0; s8 < 8; ++s8)
            o = MFMA16(pf[s8], vf[s8], o);

        // write C' strip: lane holds out[q=quad*4+r][e=l&15<8]
        if (q16 < 8){
            #pragma unroll
            for (int r = 0; r < 4; ++r){
                int row = qs*16 + quad*4 + r;
                smem[CB + row*68 + h*8 + q16] = f2h(o[r]);
            }
        }
    }

    __syncthreads();

    // ---- fc: wave w handles output rows w*16..w*16+15 ----
    const int w = h;
    half4 af[4];
    #pragma unroll
    for (int ks = 0; ks < 4; ++ks)
        af[ks] = *(const half4*)(smem + CB + (w*16 + q16)*68 + ks*16 + quad*4);

    #pragma unroll
    for (int nt = 0; nt < 4; ++nt){
        f32x4 a = zz;
        #pragma unroll
        for (int ks = 0; ks < 4; ++ks){
            half4 bf = *(const half4*)(smem + WB + (nt*16 + q16)*68 + ks*16 + quad*4);
            a = MFMA16(af[ks], bf, a);
        }
        float bb = bo[nt*16 + q16];
        #pragma unroll
        for (int r = 0; r < 4; ++r){
            int row = w*16 + quad*4 + r;
            Out[base + (long)row*4096 + nt*16 + q16] = a[r] + bb;
        }
    }
}

extern "C" void kernel_launch(void* const* d_in, const int* in_sizes, int n_in,
                              void* d_out, int out_size, void* d_ws, size_t ws_size,
                              hipStream_t stream)
{
    const float* V  = (const float*)d_in[0];
    const float* K  = (const float*)d_in[1];
    const float* Q  = (const float*)d_in[2];
    const float* Wv = (const float*)d_in[3];
    const float* Wk = (const float*)d_in[4];
    const float* Wq = (const float*)d_in[5];
    const float* Wo = (const float*)d_in[6];
    const float* bo = (const float*)d_in[7];

    sattn_kernel<<<dim3(512), dim3(512), 0, stream>>>(
        V, K, Q, Wv, Wk, Wq, Wo, bo, (float*)d_out);
}